// Round 15
// baseline (489.130 us; speedup 1.0000x reference)
//
#include <hip/hip_runtime.h>
#include <math.h>

#define NBLEND 24
#define HDIM 128
#define KQ 32                    // k-columns per wave (4-way split)
#define MAX_STEPS 10
#define CVG_T 1e-5f
#define DVG_T 1.0f
#define EPS_B 1e-6f

typedef float v2f __attribute__((ext_vector_type(2)));

#if __has_builtin(__builtin_elementwise_fma)
#define VFMA(a, b, c) __builtin_elementwise_fma((a), (b), (c))
#else
static __device__ __forceinline__ v2f VFMA(v2f a, v2f b, v2f c) {
    v2f r; r.x = fmaf(a.x, b.x, c.x); r.y = fmaf(a.y, b.y, c.y); return r;
}
#endif

__device__ __forceinline__ float softplus_f(float x) {
    // jax.nn.softplus: max(x,0) + log1p(exp(-|x|)), numerically stable
    float e = __expf(-fabsf(x));
    return fmaxf(x, 0.0f) + __logf(1.0f + e);
}

// One g(x) evaluation, 4-way k-split + h0 de-dup through LDS (R14 body,
// 311 us). Wave w computes h0 rows [w*32,w*32+32) -> LDS h[128][64]
// (lane-indexed, conflict-free), all waves read h back; W1/W2 slices via
// wave-uniform s_load (SGPR broadcast free; VMEM/LDS broadcast measured
// slower R7/R10). Logit exchange aliases the h buffer (barrier-disciplined).
// All four waves hold bit-identical results.
__device__ __forceinline__ void eval_g_quad(
    float* __restrict__ hbuf,     // 32 KB: h[128][64] / part[4][12][64] union
    int w, int lane,
    const float* __restrict__ W0, const float* __restrict__ b0,
    const float* __restrict__ W1, const float* __restrict__ b1,
    const float* __restrict__ W2, const float* __restrict__ b2,
    const float* __restrict__ tfs,
    float x0, float x1, float x2,
    float xd0, float xd1, float xd2,
    float& g0, float& g1, float& g2)
{
    v2f* part = (v2f*)hbuf;       // part[w][m2][lane] = part[(w*12+m2)*64+lane]
    v2f vx0 = {x0, x0}, vx1 = {x1, x1}, vx2 = {x2, x2};

    // ---- phase 1: own h0 slice -> LDS ----
    {
        const int jb = w * KQ;
        #pragma unroll 4
        for (int jj = 0; jj < KQ; jj += 2) {
            const int j = jb + jj;
            v2f z = *(const v2f*)(b0 + j);
            z = VFMA(vx0, *(const v2f*)(W0 + j), z);
            z = VFMA(vx1, *(const v2f*)(W0 + HDIM + j), z);
            z = VFMA(vx2, *(const v2f*)(W0 + 2 * HDIM + j), z);
            hbuf[j * 64 + lane]       = softplus_f(z.x);
            hbuf[(j + 1) * 64 + lane] = softplus_f(z.y);
        }
    }
    __syncthreads();   // h complete

    // ---- phase 2: rank-1 accumulate, h from LDS, W1 slice via s_load ----
    v2f acc[KQ / 2];
    {
        const v2f* __restrict__ b1v = (const v2f*)(b1 + w * KQ);
        #pragma unroll
        for (int kk = 0; kk < KQ / 2; ++kk) acc[kk] = b1v[kk];
    }
    const float* __restrict__ W1h = W1 + w * KQ;
    #pragma unroll 4
    for (int j = 0; j < HDIM; j += 2) {
        float ha = hbuf[j * 64 + lane];
        float hb = hbuf[(j + 1) * 64 + lane];
        const v2f* __restrict__ r0 = (const v2f*)(W1h + j * HDIM);
        const v2f* __restrict__ r1 = (const v2f*)(W1h + (j + 1) * HDIM);
        v2f hva = {ha, ha}, hvb = {hb, hb};
        #pragma unroll
        for (int kk = 0; kk < KQ / 2; ++kk) acc[kk] = VFMA(hva, r0[kk], acc[kk]);
        #pragma unroll
        for (int kk = 0; kk < KQ / 2; ++kk) acc[kk] = VFMA(hvb, r1[kk], acc[kk]);
    }
    #pragma unroll
    for (int kk = 0; kk < KQ / 2; ++kk) {
        acc[kk].x = softplus_f(acc[kk].x);
        acc[kk].y = softplus_f(acc[kk].y);
    }

    // raw partial logits over own k-slice (b2 added in fixed order below)
    v2f lgp[NBLEND / 2];
    #pragma unroll
    for (int m2 = 0; m2 < NBLEND / 2; ++m2) lgp[m2] = (v2f){0.f, 0.f};
    const float* __restrict__ W2h = W2 + w * KQ * NBLEND;
    #pragma unroll
    for (int kk = 0; kk < KQ; ++kk) {
        float h1 = (kk & 1) ? acc[kk >> 1].y : acc[kk >> 1].x;
        v2f hv = {h1, h1};
        const v2f* __restrict__ w2r = (const v2f*)(W2h + kk * NBLEND);
        #pragma unroll
        for (int m2 = 0; m2 < NBLEND / 2; ++m2) lgp[m2] = VFMA(hv, w2r[m2], lgp[m2]);
    }

    __syncthreads();   // all phase-2 h reads done; safe to overwrite via part
    #pragma unroll
    for (int m2 = 0; m2 < NBLEND / 2; ++m2) part[(w * 12 + m2) * 64 + lane] = lgp[m2];
    __syncthreads();
    v2f lg[NBLEND / 2];
    {
        const v2f* __restrict__ b2v = (const v2f*)b2;
        #pragma unroll
        for (int m2 = 0; m2 < NBLEND / 2; ++m2)
            lg[m2] = ((b2v[m2] + part[(0 * 12 + m2) * 64 + lane])
                      + part[(1 * 12 + m2) * 64 + lane])
                     + (part[(2 * 12 + m2) * 64 + lane]
                        + part[(3 * 12 + m2) * 64 + lane]);
    }
    __syncthreads();   // part reads done; next phase-1 may overwrite

    // two-pass softmax over 24 logits (matches jax.nn.softmax)
    float M = -3.0e38f;
    #pragma unroll
    for (int m2 = 0; m2 < NBLEND / 2; ++m2)
        M = fmaxf(M, fmaxf(lg[m2].x, lg[m2].y));

    float S = 0.f;
    v2f T[6];
    #pragma unroll
    for (int t = 0; t < 6; ++t) T[t] = (v2f){0.f, 0.f};
    #pragma unroll
    for (int m = 0; m < NBLEND; ++m) {
        float lgm = (m & 1) ? lg[m >> 1].y : lg[m >> 1].x;
        float e = __expf(lgm - M);
        S += e;
        const v2f* __restrict__ tf = (const v2f*)(tfs + m * 12);
        v2f ev = {e, e};
        #pragma unroll
        for (int t = 0; t < 6; ++t) T[t] = VFMA(ev, tf[t], T[t]);
    }
    float inv = 1.0f / S;
    g0 = inv * fmaf(T[0].x, x0, fmaf(T[0].y, x1, fmaf(T[1].x, x2, T[1].y))) - xd0;
    g1 = inv * fmaf(T[2].x, x0, fmaf(T[2].y, x1, fmaf(T[3].x, x2, T[3].y))) - xd1;
    g2 = inv * fmaf(T[4].x, x0, fmaf(T[4].y, x1, fmaf(T[5].x, x2, T[5].y))) - xd2;
}

// Full Broyden solve for one 64-point chunk (R14 loop body, unchanged math).
__device__ __forceinline__ void solve_chunk(
    float* __restrict__ hbuf, int w, int lane, int n, int N,
    const float* __restrict__ xd_p, const float* __restrict__ x_init,
    const float* __restrict__ Jinv_init, const float* __restrict__ tfs,
    const float* __restrict__ W0, const float* __restrict__ b0,
    const float* __restrict__ W1, const float* __restrict__ b1,
    const float* __restrict__ W2, const float* __restrict__ b2,
    float* __restrict__ out)
{
    float xd0 = xd_p[n * 3 + 0], xd1 = xd_p[n * 3 + 1], xd2 = xd_p[n * 3 + 2];
    float x0 = x_init[n * 3 + 0], x1 = x_init[n * 3 + 1], x2 = x_init[n * 3 + 2];
    float J0 = Jinv_init[n * 9 + 0], J1 = Jinv_init[n * 9 + 1], J2 = Jinv_init[n * 9 + 2];
    float J3 = Jinv_init[n * 9 + 3], J4 = Jinv_init[n * 9 + 4], J5 = Jinv_init[n * 9 + 5];
    float J6 = Jinv_init[n * 9 + 6], J7 = Jinv_init[n * 9 + 7], J8 = Jinv_init[n * 9 + 8];

    float g0, g1, g2;
    eval_g_quad(hbuf, w, lane, W0, b0, W1, b1, W2, b2, tfs,
                x0, x1, x2, xd0, xd1, xd2, g0, g1, g2);

    float u0 = -(fmaf(J0, g0, fmaf(J1, g1, J2 * g2)));
    float u1 = -(fmaf(J3, g0, fmaf(J4, g1, J5 * g2)));
    float u2 = -(fmaf(J6, g0, fmaf(J7, g1, J8 * g2)));

    float gn_opt = sqrtf(g0 * g0 + g1 * g1 + g2 * g2);
    float xo0 = x0, xo1 = x1, xo2 = x2;
    bool ids = true;   // reference initializes ids = ones(bool)

    for (int step = 0; step < MAX_STEPS; ++step) {
        // identical ids in all 4 waves -> identical ballot -> uniform break
        if (__ballot(ids) == 0ull) break;

        float dx0 = ids ? u0 : 0.f, dx1 = ids ? u1 : 0.f, dx2 = ids ? u2 : 0.f;
        x0 += dx0; x1 += dx1; x2 += dx2;

        float ng0, ng1, ng2;
        eval_g_quad(hbuf, w, lane, W0, b0, W1, b1, W2, b2, tfs,
                    x0, x1, x2, xd0, xd1, xd2, ng0, ng1, ng2);
        float dg0 = ng0 - g0, dg1 = ng1 - g1, dg2 = ng2 - g2;
        g0 = ng0; g1 = ng1; g2 = ng2;

        float gn = sqrtf(g0 * g0 + g1 * g1 + g2 * g2);
        bool better = gn < gn_opt;              // false for NaN (matches jnp.where)
        if (better) { gn_opt = gn; xo0 = x0; xo1 = x1; xo2 = x2; }
        bool ids_new = (gn_opt > CVG_T) && (gn < DVG_T);

        float vT0 = fmaf(dx0, J0, fmaf(dx1, J3, dx2 * J6));
        float vT1 = fmaf(dx0, J1, fmaf(dx1, J4, dx2 * J7));
        float vT2 = fmaf(dx0, J2, fmaf(dx1, J5, dx2 * J8));
        float a0 = dx0 - fmaf(J0, dg0, fmaf(J1, dg1, J2 * dg2));
        float a1 = dx1 - fmaf(J3, dg0, fmaf(J4, dg1, J5 * dg2));
        float a2 = dx2 - fmaf(J6, dg0, fmaf(J7, dg1, J8 * dg2));
        float bb = fmaf(vT0, dg0, fmaf(vT1, dg1, vT2 * dg2));
        bb += (bb >= 0.f) ? EPS_B : -EPS_B;
        // select (NOT multiply) so NaN can't leak into J when masked off
        float iu0 = ids_new ? (a0 / bb) : 0.f;
        float iu1 = ids_new ? (a1 / bb) : 0.f;
        float iu2 = ids_new ? (a2 / bb) : 0.f;
        J0 = fmaf(iu0, vT0, J0); J1 = fmaf(iu0, vT1, J1); J2 = fmaf(iu0, vT2, J2);
        J3 = fmaf(iu1, vT0, J3); J4 = fmaf(iu1, vT1, J4); J5 = fmaf(iu1, vT2, J5);
        J6 = fmaf(iu2, vT0, J6); J7 = fmaf(iu2, vT1, J7); J8 = fmaf(iu2, vT2, J8);

        u0 = -(fmaf(J0, g0, fmaf(J1, g1, J2 * g2)));
        u1 = -(fmaf(J3, g0, fmaf(J4, g1, J5 * g2)));
        u2 = -(fmaf(J6, g0, fmaf(J7, g1, J8 * g2)));
        ids = ids_new;
    }

    // outputs: x_opt (N,3,1) | gn_opt (N) | valid (N) as 0.0/1.0
    if (w == 0) {
        out[n * 3 + 0] = xo0;
        out[n * 3 + 1] = xo1;
        out[n * 3 + 2] = xo2;
        out[3 * N + n] = gn_opt;
        out[4 * N + n] = (gn_opt < CVG_T) ? 1.0f : 0.0f;
    }
}

// Persistent work-stealing monolith: ~5 resident blocks/CU; each block pulls
// 64-point chunks from a global counter until exhausted. Removes the
// dispatch-round drain tail (R14: avg occupancy 38.9% vs 62.5% resident —
// the VALUBusy 86->70 drop was tail idle, not steady-state stall).
// Chunk->block assignment varies run to run, but each point's math is
// self-contained and identical -> output deterministic.
__global__ void __launch_bounds__(256)
broyden_persist_kernel(const float* __restrict__ xd_p,
                       const float* __restrict__ x_init,
                       const float* __restrict__ Jinv_init,
                       const float* __restrict__ tfs,
                       const float* __restrict__ W0, const float* __restrict__ b0,
                       const float* __restrict__ W1, const float* __restrict__ b1,
                       const float* __restrict__ W2, const float* __restrict__ b2,
                       float* __restrict__ out, int* __restrict__ ctr,
                       int nchunks, int N)
{
    __shared__ __align__(16) float hbuf[HDIM * 64];   // 32 KB (h/part/chunk union)
    const int tid = threadIdx.x;
    const int lane = tid & 63;
    const int w = __builtin_amdgcn_readfirstlane(tid >> 6);   // 0..3

    for (;;) {
        // pull next chunk; broadcast via hbuf[0] (free between evals)
        if (tid == 0) ((int*)hbuf)[0] = atomicAdd(ctr, 1);
        __syncthreads();
        const int chunk = ((int*)hbuf)[0];
        __syncthreads();   // all read before phase-1 overwrites hbuf[0]
        if (chunk >= nchunks) break;           // uniform exit

        const int n = chunk * 64 + lane;       // N is a multiple of 64
        solve_chunk(hbuf, w, lane, n, N, xd_p, x_init, Jinv_init, tfs,
                    W0, b0, W1, b1, W2, b2, out);
    }
}

// fallback: static-grid monolith (R14), used only if d_ws lacks 16 bytes
__global__ void __launch_bounds__(256)
broyden_quad_kernel(const float* __restrict__ xd_p,
                    const float* __restrict__ x_init,
                    const float* __restrict__ Jinv_init,
                    const float* __restrict__ tfs,
                    const float* __restrict__ W0, const float* __restrict__ b0,
                    const float* __restrict__ W1, const float* __restrict__ b1,
                    const float* __restrict__ W2, const float* __restrict__ b2,
                    float* __restrict__ out, int N)
{
    __shared__ __align__(16) float hbuf[HDIM * 64];   // 32 KB
    const int tid = threadIdx.x;
    const int lane = tid & 63;
    const int w = __builtin_amdgcn_readfirstlane(tid >> 6);
    const int n = blockIdx.x * 64 + lane;
    solve_chunk(hbuf, w, lane, n, N, xd_p, x_init, Jinv_init, tfs,
                W0, b0, W1, b1, W2, b2, out);
}

extern "C" void kernel_launch(void* const* d_in, const int* in_sizes, int n_in,
                              void* d_out, int out_size, void* d_ws, size_t ws_size,
                              hipStream_t stream) {
    const float* xd     = (const float*)d_in[0];
    const float* x_init = (const float*)d_in[1];
    const float* Jinv   = (const float*)d_in[2];
    const float* tfs    = (const float*)d_in[3];
    const float* W0     = (const float*)d_in[4];
    const float* b0     = (const float*)d_in[5];
    const float* W1     = (const float*)d_in[6];
    const float* b1     = (const float*)d_in[7];
    const float* W2     = (const float*)d_in[8];
    const float* b2     = (const float*)d_in[9];
    float* out = (float*)d_out;

    const int N = in_sizes[0] / 3;
    const int nchunks = (N + 63) / 64;

    if (ws_size >= 16) {
        int* ctr = (int*)d_ws;
        hipMemsetAsync(ctr, 0, 16, stream);
        // ~5 resident blocks/CU x 256 CUs; extra blocks exit immediately
        const int nblk = (nchunks < 1280) ? nchunks : 1280;
        hipLaunchKernelGGL(broyden_persist_kernel, dim3(nblk), dim3(256), 0, stream,
                           xd, x_init, Jinv, tfs, W0, b0, W1, b1, W2, b2,
                           out, ctr, nchunks, N);
    } else {
        hipLaunchKernelGGL(broyden_quad_kernel, dim3(nchunks), dim3(256), 0, stream,
                           xd, x_init, Jinv, tfs, W0, b0, W1, b1, W2, b2, out, N);
    }
}

// Round 16
// 344.046 us; speedup vs baseline: 1.4217x; 1.4217x over previous
//
#include <hip/hip_runtime.h>
#include <math.h>

#define NBLEND 24
#define HDIM 128
#define KQ 32                    // k-columns per wave (4-way split)
#define MAX_STEPS 10
#define CVG_T 1e-5f
#define DVG_T 1.0f
#define EPS_B 1e-6f

typedef float v2f __attribute__((ext_vector_type(2)));

#if __has_builtin(__builtin_elementwise_fma)
#define VFMA(a, b, c) __builtin_elementwise_fma((a), (b), (c))
#else
static __device__ __forceinline__ v2f VFMA(v2f a, v2f b, v2f c) {
    v2f r; r.x = fmaf(a.x, b.x, c.x); r.y = fmaf(a.y, b.y, c.y); return r;
}
#endif

__device__ __forceinline__ float softplus_f(float x) {
    // jax.nn.softplus: max(x,0) + log1p(exp(-|x|)), numerically stable
    float e = __expf(-fabsf(x));
    return fmaxf(x, 0.0f) + __logf(1.0f + e);
}

// One g(x) evaluation, 4-way k-split + h0 de-dup (R14 math, BIT-IDENTICAL),
// restructured to fit 16 KB LDS so 8 blocks/CU are resident (R14's 32 KB
// allowed only 5 -> 1.6 dispatch rounds -> drain tail; occupancy 38.9%,
// VALUBusy 70% vs 86% at higher residency).
//  - h computed in two 64-row halves into a 16 KB buffer (same values,
//    same j accumulation order).
//  - logit exchange in two 2-wave rounds through the same buffer with the
//    EXACT R14 parenthesization ((b2+p0)+p1)+(p2+p3).
// Weights stay on the wave-uniform scalar path (SGPR broadcast free;
// VMEM/LDS broadcast measured slower, R7/R10). 8 barriers/eval, all
// block-uniform; hidden at 8 blocks/CU.
__device__ __forceinline__ void eval_g_quad(
    float* __restrict__ hbuf,     // 16 KB: h_half[64][64] / xch[2][12][64] union
    int w, int lane,
    const float* __restrict__ W0, const float* __restrict__ b0,
    const float* __restrict__ W1, const float* __restrict__ b1,
    const float* __restrict__ W2, const float* __restrict__ b2,
    const float* __restrict__ tfs,
    float x0, float x1, float x2,
    float xd0, float xd1, float xd2,
    float& g0, float& g1, float& g2)
{
    v2f* xch = (v2f*)hbuf;        // xch[r][m2][lane] = xch[(r*12+m2)*64+lane]
    v2f vx0 = {x0, x0}, vx1 = {x1, x1}, vx2 = {x2, x2};

    v2f acc[KQ / 2];
    {
        const v2f* __restrict__ b1v = (const v2f*)(b1 + w * KQ);
        #pragma unroll
        for (int kk = 0; kk < KQ / 2; ++kk) acc[kk] = b1v[kk];
    }
    const float* __restrict__ W1h = W1 + w * KQ;

    // ---- two h-halves: compute 64 rows -> LDS, then accumulate them ----
    #pragma unroll 1
    for (int half = 0; half < 2; ++half) {
        __syncthreads();   // WAR: prior reads of hbuf complete
        {
            const int jb = half * 64 + w * 16;   // 16 rows per wave per half
            #pragma unroll 4
            for (int jj = 0; jj < 16; jj += 2) {
                const int j = jb + jj;
                v2f z = *(const v2f*)(b0 + j);
                z = VFMA(vx0, *(const v2f*)(W0 + j), z);
                z = VFMA(vx1, *(const v2f*)(W0 + HDIM + j), z);
                z = VFMA(vx2, *(const v2f*)(W0 + 2 * HDIM + j), z);
                hbuf[(j & 63) * 64 + lane]       = softplus_f(z.x);
                hbuf[((j + 1) & 63) * 64 + lane] = softplus_f(z.y);
            }
        }
        __syncthreads();   // h half complete

        const int j0 = half * 64;
        #pragma unroll 2
        for (int jj = 0; jj < 64; jj += 2) {
            const int j = j0 + jj;
            float ha = hbuf[jj * 64 + lane];
            float hb = hbuf[(jj + 1) * 64 + lane];
            const v2f* __restrict__ r0 = (const v2f*)(W1h + j * HDIM);
            const v2f* __restrict__ r1 = (const v2f*)(W1h + (j + 1) * HDIM);
            v2f hva = {ha, ha}, hvb = {hb, hb};
            #pragma unroll
            for (int kk = 0; kk < KQ / 2; ++kk) acc[kk] = VFMA(hva, r0[kk], acc[kk]);
            #pragma unroll
            for (int kk = 0; kk < KQ / 2; ++kk) acc[kk] = VFMA(hvb, r1[kk], acc[kk]);
        }
    }
    #pragma unroll
    for (int kk = 0; kk < KQ / 2; ++kk) {
        acc[kk].x = softplus_f(acc[kk].x);
        acc[kk].y = softplus_f(acc[kk].y);
    }

    // raw partial logits over own k-slice (b2 added in fixed order below)
    v2f lgp[NBLEND / 2];
    #pragma unroll
    for (int m2 = 0; m2 < NBLEND / 2; ++m2) lgp[m2] = (v2f){0.f, 0.f};
    const float* __restrict__ W2h = W2 + w * KQ * NBLEND;
    #pragma unroll
    for (int kk = 0; kk < KQ; ++kk) {
        float h1 = (kk & 1) ? acc[kk >> 1].y : acc[kk >> 1].x;
        v2f hv = {h1, h1};
        const v2f* __restrict__ w2r = (const v2f*)(W2h + kk * NBLEND);
        #pragma unroll
        for (int m2 = 0; m2 < NBLEND / 2; ++m2) lgp[m2] = VFMA(hv, w2r[m2], lgp[m2]);
    }

    // ---- exchange in two 2-wave rounds (fits 12 KB of the 16 KB buffer),
    //      summation order IDENTICAL to R14: ((b2+p0)+p1) + (p2+p3) ----
    __syncthreads();   // phase-2 h reads done; safe to overwrite hbuf
    if (w < 2) {
        #pragma unroll
        for (int m2 = 0; m2 < NBLEND / 2; ++m2)
            xch[(w * 12 + m2) * 64 + lane] = lgp[m2];
    }
    __syncthreads();
    v2f lg[NBLEND / 2];
    {
        const v2f* __restrict__ b2v = (const v2f*)b2;
        #pragma unroll
        for (int m2 = 0; m2 < NBLEND / 2; ++m2)
            lg[m2] = (b2v[m2] + xch[(0 * 12 + m2) * 64 + lane])
                     + xch[(1 * 12 + m2) * 64 + lane];
    }
    __syncthreads();   // WAR: round-1 reads done
    if (w >= 2) {
        #pragma unroll
        for (int m2 = 0; m2 < NBLEND / 2; ++m2)
            xch[((w - 2) * 12 + m2) * 64 + lane] = lgp[m2];
    }
    __syncthreads();
    #pragma unroll
    for (int m2 = 0; m2 < NBLEND / 2; ++m2)
        lg[m2] += (xch[(0 * 12 + m2) * 64 + lane]
                   + xch[(1 * 12 + m2) * 64 + lane]);
    // (next LDS write is the next eval's h half-0, behind its WAR barrier)

    // two-pass softmax over 24 logits (matches jax.nn.softmax)
    float M = -3.0e38f;
    #pragma unroll
    for (int m2 = 0; m2 < NBLEND / 2; ++m2)
        M = fmaxf(M, fmaxf(lg[m2].x, lg[m2].y));

    float S = 0.f;
    v2f T[6];
    #pragma unroll
    for (int t = 0; t < 6; ++t) T[t] = (v2f){0.f, 0.f};
    #pragma unroll
    for (int m = 0; m < NBLEND; ++m) {
        float lgm = (m & 1) ? lg[m >> 1].y : lg[m >> 1].x;
        float e = __expf(lgm - M);
        S += e;
        const v2f* __restrict__ tf = (const v2f*)(tfs + m * 12);
        v2f ev = {e, e};
        #pragma unroll
        for (int t = 0; t < 6; ++t) T[t] = VFMA(ev, tf[t], T[t]);
    }
    float inv = 1.0f / S;
    g0 = inv * fmaf(T[0].x, x0, fmaf(T[0].y, x1, fmaf(T[1].x, x2, T[1].y))) - xd0;
    g1 = inv * fmaf(T[2].x, x0, fmaf(T[2].y, x1, fmaf(T[3].x, x2, T[3].y))) - xd1;
    g2 = inv * fmaf(T[4].x, x0, fmaf(T[4].y, x1, fmaf(T[5].x, x2, T[5].y))) - xd2;
}

// Monolithic Broyden solver: 1 block = 4 waves = 64 points; static grid
// (R15 proved persistent work-stealing costs more VGPR than it saves tail).
// All four waves carry bit-identical state -> identical ballot -> uniform
// break, barriers aligned. Frozen lanes take dx=0: exact fixed point
// (dg=0 -> a=0 -> iu=0; NaN guarded by selects).
__global__ void __launch_bounds__(256)
broyden_quad_kernel(const float* __restrict__ xd_p,
                    const float* __restrict__ x_init,
                    const float* __restrict__ Jinv_init,
                    const float* __restrict__ tfs,
                    const float* __restrict__ W0, const float* __restrict__ b0,
                    const float* __restrict__ W1, const float* __restrict__ b1,
                    const float* __restrict__ W2, const float* __restrict__ b2,
                    float* __restrict__ out, int N)
{
    __shared__ __align__(16) float hbuf[64 * 64];   // 16 KB (h-half / xch union)
    const int tid = threadIdx.x;
    const int lane = tid & 63;
    const int w = __builtin_amdgcn_readfirstlane(tid >> 6);   // 0..3
    const int n = blockIdx.x * 64 + lane;    // N = 131072 = 2048*64 exact

    float xd0 = xd_p[n * 3 + 0], xd1 = xd_p[n * 3 + 1], xd2 = xd_p[n * 3 + 2];
    float x0 = x_init[n * 3 + 0], x1 = x_init[n * 3 + 1], x2 = x_init[n * 3 + 2];
    float J0 = Jinv_init[n * 9 + 0], J1 = Jinv_init[n * 9 + 1], J2 = Jinv_init[n * 9 + 2];
    float J3 = Jinv_init[n * 9 + 3], J4 = Jinv_init[n * 9 + 4], J5 = Jinv_init[n * 9 + 5];
    float J6 = Jinv_init[n * 9 + 6], J7 = Jinv_init[n * 9 + 7], J8 = Jinv_init[n * 9 + 8];

    float g0, g1, g2;
    eval_g_quad(hbuf, w, lane, W0, b0, W1, b1, W2, b2, tfs,
                x0, x1, x2, xd0, xd1, xd2, g0, g1, g2);

    float u0 = -(fmaf(J0, g0, fmaf(J1, g1, J2 * g2)));
    float u1 = -(fmaf(J3, g0, fmaf(J4, g1, J5 * g2)));
    float u2 = -(fmaf(J6, g0, fmaf(J7, g1, J8 * g2)));

    float gn_opt = sqrtf(g0 * g0 + g1 * g1 + g2 * g2);
    float xo0 = x0, xo1 = x1, xo2 = x2;
    bool ids = true;   // reference initializes ids = ones(bool)

    for (int step = 0; step < MAX_STEPS; ++step) {
        // identical ids in all 4 waves -> identical ballot -> uniform break
        if (__ballot(ids) == 0ull) break;

        float dx0 = ids ? u0 : 0.f, dx1 = ids ? u1 : 0.f, dx2 = ids ? u2 : 0.f;
        x0 += dx0; x1 += dx1; x2 += dx2;

        float ng0, ng1, ng2;
        eval_g_quad(hbuf, w, lane, W0, b0, W1, b1, W2, b2, tfs,
                    x0, x1, x2, xd0, xd1, xd2, ng0, ng1, ng2);
        float dg0 = ng0 - g0, dg1 = ng1 - g1, dg2 = ng2 - g2;
        g0 = ng0; g1 = ng1; g2 = ng2;

        float gn = sqrtf(g0 * g0 + g1 * g1 + g2 * g2);
        bool better = gn < gn_opt;              // false for NaN (matches jnp.where)
        if (better) { gn_opt = gn; xo0 = x0; xo1 = x1; xo2 = x2; }
        bool ids_new = (gn_opt > CVG_T) && (gn < DVG_T);

        float vT0 = fmaf(dx0, J0, fmaf(dx1, J3, dx2 * J6));
        float vT1 = fmaf(dx0, J1, fmaf(dx1, J4, dx2 * J7));
        float vT2 = fmaf(dx0, J2, fmaf(dx1, J5, dx2 * J8));
        float a0 = dx0 - fmaf(J0, dg0, fmaf(J1, dg1, J2 * dg2));
        float a1 = dx1 - fmaf(J3, dg0, fmaf(J4, dg1, J5 * dg2));
        float a2 = dx2 - fmaf(J6, dg0, fmaf(J7, dg1, J8 * dg2));
        float bb = fmaf(vT0, dg0, fmaf(vT1, dg1, vT2 * dg2));
        bb += (bb >= 0.f) ? EPS_B : -EPS_B;
        // select (NOT multiply) so NaN can't leak into J when masked off
        float iu0 = ids_new ? (a0 / bb) : 0.f;
        float iu1 = ids_new ? (a1 / bb) : 0.f;
        float iu2 = ids_new ? (a2 / bb) : 0.f;
        J0 = fmaf(iu0, vT0, J0); J1 = fmaf(iu0, vT1, J1); J2 = fmaf(iu0, vT2, J2);
        J3 = fmaf(iu1, vT0, J3); J4 = fmaf(iu1, vT1, J4); J5 = fmaf(iu1, vT2, J5);
        J6 = fmaf(iu2, vT0, J6); J7 = fmaf(iu2, vT1, J7); J8 = fmaf(iu2, vT2, J8);

        u0 = -(fmaf(J0, g0, fmaf(J1, g1, J2 * g2)));
        u1 = -(fmaf(J3, g0, fmaf(J4, g1, J5 * g2)));
        u2 = -(fmaf(J6, g0, fmaf(J7, g1, J8 * g2)));
        ids = ids_new;
    }

    // outputs: x_opt (N,3,1) | gn_opt (N) | valid (N) as 0.0/1.0
    if (w == 0) {
        out[n * 3 + 0] = xo0;
        out[n * 3 + 1] = xo1;
        out[n * 3 + 2] = xo2;
        out[3 * N + n] = gn_opt;
        out[4 * N + n] = (gn_opt < CVG_T) ? 1.0f : 0.0f;
    }
}

extern "C" void kernel_launch(void* const* d_in, const int* in_sizes, int n_in,
                              void* d_out, int out_size, void* d_ws, size_t ws_size,
                              hipStream_t stream) {
    const float* xd     = (const float*)d_in[0];
    const float* x_init = (const float*)d_in[1];
    const float* Jinv   = (const float*)d_in[2];
    const float* tfs    = (const float*)d_in[3];
    const float* W0     = (const float*)d_in[4];
    const float* b0     = (const float*)d_in[5];
    const float* W1     = (const float*)d_in[6];
    const float* b1     = (const float*)d_in[7];
    const float* W2     = (const float*)d_in[8];
    const float* b2     = (const float*)d_in[9];
    float* out = (float*)d_out;

    const int N = in_sizes[0] / 3;
    dim3 block(256);                 // 4 waves, 64 points per block
    dim3 grid((N + 63) / 64);        // 2048 blocks = exactly 8/CU, one round

    hipLaunchKernelGGL(broyden_quad_kernel, grid, block, 0, stream,
                       xd, x_init, Jinv, tfs, W0, b0, W1, b1, W2, b2, out, N);
}

// Round 18
// 309.405 us; speedup vs baseline: 1.5809x; 1.1120x over previous
//
#include <hip/hip_runtime.h>
#include <math.h>

#define NBLEND 24
#define HDIM 128
#define KQ 32                    // k-columns per wave (4-way split)
#define MAX_STEPS 10
#define CVG_T 1e-5f
#define DVG_T 1.0f
#define EPS_B 1e-6f

typedef float v2f __attribute__((ext_vector_type(2)));

#if __has_builtin(__builtin_elementwise_fma)
#define VFMA(a, b, c) __builtin_elementwise_fma((a), (b), (c))
#else
static __device__ __forceinline__ v2f VFMA(v2f a, v2f b, v2f c) {
    v2f r; r.x = fmaf(a.x, b.x, c.x); r.y = fmaf(a.y, b.y, c.y); return r;
}
#endif

__device__ __forceinline__ float softplus_f(float x) {
    // jax.nn.softplus: max(x,0) + log1p(exp(-|x|)), numerically stable
    float e = __expf(-fabsf(x));
    return fmaxf(x, 0.0f) + __logf(1.0f + e);
}

// One g(x) evaluation, 4-way k-split + h0 de-duplication through LDS
// (R14 configuration — the measured optimum at 311 us; R15 work-stealing,
// R16 16KB-restructure, and R17 bf16-h all regressed or failed).
// Wave w computes h0 rows [w*32,w*32+32) -> LDS h[128][64] (lane-indexed,
// conflict-free), all waves read h back; W1/W2 slices via wave-uniform
// s_load (SGPR broadcast is free in the VALU operand network; VMEM/LDS
// broadcast measured slower, R7/R10). Logit exchange aliases the h buffer
// (barrier-disciplined). All four waves hold bit-identical results.
__device__ __forceinline__ void eval_g_quad(
    float* __restrict__ hbuf,     // 32 KB: h[128][64] / part[4][12][64] union
    int w, int lane,
    const float* __restrict__ W0, const float* __restrict__ b0,
    const float* __restrict__ W1, const float* __restrict__ b1,
    const float* __restrict__ W2, const float* __restrict__ b2,
    const float* __restrict__ tfs,
    float x0, float x1, float x2,
    float xd0, float xd1, float xd2,
    float& g0, float& g1, float& g2)
{
    v2f* part = (v2f*)hbuf;       // part[w][m2][lane] = part[(w*12+m2)*64+lane]
    v2f vx0 = {x0, x0}, vx1 = {x1, x1}, vx2 = {x2, x2};

    // ---- phase 1: own h0 slice -> LDS ----
    {
        const int jb = w * KQ;
        #pragma unroll 4
        for (int jj = 0; jj < KQ; jj += 2) {
            const int j = jb + jj;
            v2f z = *(const v2f*)(b0 + j);
            z = VFMA(vx0, *(const v2f*)(W0 + j), z);
            z = VFMA(vx1, *(const v2f*)(W0 + HDIM + j), z);
            z = VFMA(vx2, *(const v2f*)(W0 + 2 * HDIM + j), z);
            hbuf[j * 64 + lane]       = softplus_f(z.x);
            hbuf[(j + 1) * 64 + lane] = softplus_f(z.y);
        }
    }
    __syncthreads();   // h complete

    // ---- phase 2: rank-1 accumulate, h from LDS, W1 slice via s_load ----
    v2f acc[KQ / 2];
    {
        const v2f* __restrict__ b1v = (const v2f*)(b1 + w * KQ);
        #pragma unroll
        for (int kk = 0; kk < KQ / 2; ++kk) acc[kk] = b1v[kk];
    }
    const float* __restrict__ W1h = W1 + w * KQ;
    #pragma unroll 4
    for (int j = 0; j < HDIM; j += 2) {
        float ha = hbuf[j * 64 + lane];
        float hb = hbuf[(j + 1) * 64 + lane];
        const v2f* __restrict__ r0 = (const v2f*)(W1h + j * HDIM);
        const v2f* __restrict__ r1 = (const v2f*)(W1h + (j + 1) * HDIM);
        v2f hva = {ha, ha}, hvb = {hb, hb};
        #pragma unroll
        for (int kk = 0; kk < KQ / 2; ++kk) acc[kk] = VFMA(hva, r0[kk], acc[kk]);
        #pragma unroll
        for (int kk = 0; kk < KQ / 2; ++kk) acc[kk] = VFMA(hvb, r1[kk], acc[kk]);
    }
    #pragma unroll
    for (int kk = 0; kk < KQ / 2; ++kk) {
        acc[kk].x = softplus_f(acc[kk].x);
        acc[kk].y = softplus_f(acc[kk].y);
    }

    // raw partial logits over own k-slice (b2 added in fixed order below)
    v2f lgp[NBLEND / 2];
    #pragma unroll
    for (int m2 = 0; m2 < NBLEND / 2; ++m2) lgp[m2] = (v2f){0.f, 0.f};
    const float* __restrict__ W2h = W2 + w * KQ * NBLEND;
    #pragma unroll
    for (int kk = 0; kk < KQ; ++kk) {
        float h1 = (kk & 1) ? acc[kk >> 1].y : acc[kk >> 1].x;
        v2f hv = {h1, h1};
        const v2f* __restrict__ w2r = (const v2f*)(W2h + kk * NBLEND);
        #pragma unroll
        for (int m2 = 0; m2 < NBLEND / 2; ++m2) lgp[m2] = VFMA(hv, w2r[m2], lgp[m2]);
    }

    __syncthreads();   // all phase-2 h reads done; safe to overwrite via part
    #pragma unroll
    for (int m2 = 0; m2 < NBLEND / 2; ++m2) part[(w * 12 + m2) * 64 + lane] = lgp[m2];
    __syncthreads();
    v2f lg[NBLEND / 2];
    {
        const v2f* __restrict__ b2v = (const v2f*)b2;
        #pragma unroll
        for (int m2 = 0; m2 < NBLEND / 2; ++m2)
            lg[m2] = ((b2v[m2] + part[(0 * 12 + m2) * 64 + lane])
                      + part[(1 * 12 + m2) * 64 + lane])
                     + (part[(2 * 12 + m2) * 64 + lane]
                        + part[(3 * 12 + m2) * 64 + lane]);
    }
    __syncthreads();   // part reads done; next phase-1 may overwrite

    // two-pass softmax over 24 logits (matches jax.nn.softmax)
    float M = -3.0e38f;
    #pragma unroll
    for (int m2 = 0; m2 < NBLEND / 2; ++m2)
        M = fmaxf(M, fmaxf(lg[m2].x, lg[m2].y));

    float S = 0.f;
    v2f T[6];
    #pragma unroll
    for (int t = 0; t < 6; ++t) T[t] = (v2f){0.f, 0.f};
    #pragma unroll
    for (int m = 0; m < NBLEND; ++m) {
        float lgm = (m & 1) ? lg[m >> 1].y : lg[m >> 1].x;
        float e = __expf(lgm - M);
        S += e;
        const v2f* __restrict__ tf = (const v2f*)(tfs + m * 12);
        v2f ev = {e, e};
        #pragma unroll
        for (int t = 0; t < 6; ++t) T[t] = VFMA(ev, tf[t], T[t]);
    }
    float inv = 1.0f / S;
    g0 = inv * fmaf(T[0].x, x0, fmaf(T[0].y, x1, fmaf(T[1].x, x2, T[1].y))) - xd0;
    g1 = inv * fmaf(T[2].x, x0, fmaf(T[2].y, x1, fmaf(T[3].x, x2, T[3].y))) - xd1;
    g2 = inv * fmaf(T[4].x, x0, fmaf(T[4].y, x1, fmaf(T[5].x, x2, T[5].y))) - xd2;
}

// Monolithic Broyden solver: 1 block = 4 waves = 64 points (block-ballot
// early exit captures ~all the convergence win; R13 proved compaction is a
// wash, R15 proved work-stealing regresses). All four waves carry
// bit-identical state -> identical ballot -> uniform break, barriers
// aligned. Frozen lanes take dx=0: exact fixed point (dg=0 -> a=0 ->
// iu=0; NaN guarded by selects).
__global__ void __launch_bounds__(256)
broyden_quad_kernel(const float* __restrict__ xd_p,
                    const float* __restrict__ x_init,
                    const float* __restrict__ Jinv_init,
                    const float* __restrict__ tfs,
                    const float* __restrict__ W0, const float* __restrict__ b0,
                    const float* __restrict__ W1, const float* __restrict__ b1,
                    const float* __restrict__ W2, const float* __restrict__ b2,
                    float* __restrict__ out, int N)
{
    __shared__ __align__(16) float hbuf[HDIM * 64];   // 32 KB (h / part union)
    const int tid = threadIdx.x;
    const int lane = tid & 63;
    const int w = __builtin_amdgcn_readfirstlane(tid >> 6);   // 0..3
    const int n = blockIdx.x * 64 + lane;    // N = 131072 = 2048*64 exact

    float xd0 = xd_p[n * 3 + 0], xd1 = xd_p[n * 3 + 1], xd2 = xd_p[n * 3 + 2];
    float x0 = x_init[n * 3 + 0], x1 = x_init[n * 3 + 1], x2 = x_init[n * 3 + 2];
    float J0 = Jinv_init[n * 9 + 0], J1 = Jinv_init[n * 9 + 1], J2 = Jinv_init[n * 9 + 2];
    float J3 = Jinv_init[n * 9 + 3], J4 = Jinv_init[n * 9 + 4], J5 = Jinv_init[n * 9 + 5];
    float J6 = Jinv_init[n * 9 + 6], J7 = Jinv_init[n * 9 + 7], J8 = Jinv_init[n * 9 + 8];

    float g0, g1, g2;
    eval_g_quad(hbuf, w, lane, W0, b0, W1, b1, W2, b2, tfs,
                x0, x1, x2, xd0, xd1, xd2, g0, g1, g2);

    float u0 = -(fmaf(J0, g0, fmaf(J1, g1, J2 * g2)));
    float u1 = -(fmaf(J3, g0, fmaf(J4, g1, J5 * g2)));
    float u2 = -(fmaf(J6, g0, fmaf(J7, g1, J8 * g2)));

    float gn_opt = sqrtf(g0 * g0 + g1 * g1 + g2 * g2);
    float xo0 = x0, xo1 = x1, xo2 = x2;
    bool ids = true;   // reference initializes ids = ones(bool)

    for (int step = 0; step < MAX_STEPS; ++step) {
        // identical ids in all 4 waves -> identical ballot -> uniform break
        if (__ballot(ids) == 0ull) break;

        float dx0 = ids ? u0 : 0.f, dx1 = ids ? u1 : 0.f, dx2 = ids ? u2 : 0.f;
        x0 += dx0; x1 += dx1; x2 += dx2;

        float ng0, ng1, ng2;
        eval_g_quad(hbuf, w, lane, W0, b0, W1, b1, W2, b2, tfs,
                    x0, x1, x2, xd0, xd1, xd2, ng0, ng1, ng2);
        float dg0 = ng0 - g0, dg1 = ng1 - g1, dg2 = ng2 - g2;
        g0 = ng0; g1 = ng1; g2 = ng2;

        float gn = sqrtf(g0 * g0 + g1 * g1 + g2 * g2);
        bool better = gn < gn_opt;              // false for NaN (matches jnp.where)
        if (better) { gn_opt = gn; xo0 = x0; xo1 = x1; xo2 = x2; }
        bool ids_new = (gn_opt > CVG_T) && (gn < DVG_T);

        float vT0 = fmaf(dx0, J0, fmaf(dx1, J3, dx2 * J6));
        float vT1 = fmaf(dx0, J1, fmaf(dx1, J4, dx2 * J7));
        float vT2 = fmaf(dx0, J2, fmaf(dx1, J5, dx2 * J8));
        float a0 = dx0 - fmaf(J0, dg0, fmaf(J1, dg1, J2 * dg2));
        float a1 = dx1 - fmaf(J3, dg0, fmaf(J4, dg1, J5 * dg2));
        float a2 = dx2 - fmaf(J6, dg0, fmaf(J7, dg1, J8 * dg2));
        float bb = fmaf(vT0, dg0, fmaf(vT1, dg1, vT2 * dg2));
        bb += (bb >= 0.f) ? EPS_B : -EPS_B;
        // select (NOT multiply) so NaN can't leak into J when masked off
        float iu0 = ids_new ? (a0 / bb) : 0.f;
        float iu1 = ids_new ? (a1 / bb) : 0.f;
        float iu2 = ids_new ? (a2 / bb) : 0.f;
        J0 = fmaf(iu0, vT0, J0); J1 = fmaf(iu0, vT1, J1); J2 = fmaf(iu0, vT2, J2);
        J3 = fmaf(iu1, vT0, J3); J4 = fmaf(iu1, vT1, J4); J5 = fmaf(iu1, vT2, J5);
        J6 = fmaf(iu2, vT0, J6); J7 = fmaf(iu2, vT1, J7); J8 = fmaf(iu2, vT2, J8);

        u0 = -(fmaf(J0, g0, fmaf(J1, g1, J2 * g2)));
        u1 = -(fmaf(J3, g0, fmaf(J4, g1, J5 * g2)));
        u2 = -(fmaf(J6, g0, fmaf(J7, g1, J8 * g2)));
        ids = ids_new;
    }

    // outputs: x_opt (N,3,1) | gn_opt (N) | valid (N) as 0.0/1.0
    if (w == 0) {
        out[n * 3 + 0] = xo0;
        out[n * 3 + 1] = xo1;
        out[n * 3 + 2] = xo2;
        out[3 * N + n] = gn_opt;
        out[4 * N + n] = (gn_opt < CVG_T) ? 1.0f : 0.0f;
    }
}

extern "C" void kernel_launch(void* const* d_in, const int* in_sizes, int n_in,
                              void* d_out, int out_size, void* d_ws, size_t ws_size,
                              hipStream_t stream) {
    const float* xd     = (const float*)d_in[0];
    const float* x_init = (const float*)d_in[1];
    const float* Jinv   = (const float*)d_in[2];
    const float* tfs    = (const float*)d_in[3];
    const float* W0     = (const float*)d_in[4];
    const float* b0     = (const float*)d_in[5];
    const float* W1     = (const float*)d_in[6];
    const float* b1     = (const float*)d_in[7];
    const float* W2     = (const float*)d_in[8];
    const float* b2     = (const float*)d_in[9];
    float* out = (float*)d_out;

    const int N = in_sizes[0] / 3;
    dim3 block(256);                 // 4 waves, 64 points per block
    dim3 grid((N + 63) / 64);

    hipLaunchKernelGGL(broyden_quad_kernel, grid, block, 0, stream,
                       xd, x_init, Jinv, tfs, W0, b0, W1, b1, W2, b2, out, N);
}